// Round 7
// baseline (866.692 us; speedup 1.0000x reference)
//
#include <hip/hip_runtime.h>

// LightGCN on MI355X (gfx950). Round 7.
// R6 falsifications: partA invariant at ~103us under 2x occupancy, 2x per-address
// global atomics, 2x write volume -> bound by its 3-pass edge-stream structure, not
// occupancy/atomics/writes. Changes: deterministic count-matrix partition:
//   partA1: per-chunk LDS hist -> cntmat[586][293]   (1 edge pass)
//   colscanA/B: column scans -> run offsets + bucket bases (no histb/scanb/gcur)
//   partA2: cursor=precomputed, LDS rank, nt run-store (1 edge pass)
// Edge passes 3->2, kernels 11->9, zero global atomics in the sort.
// Plus: nontemporal edge-stream loads in spmm/partB so the read-once streams stop
// evicting the gather working set from L2.

#define NUSERS 100000
#define NITEMS 50000
#define NTOT   150000
#define DIM    64
#define NNZ_E  4800000

#define RPB     512                               // rows per bucket
#define RSH     9
#define NBUCK   ((NTOT + RPB - 1) / RPB)          // 293
#define CHUNK_E 8192
#define NPART   ((NNZ_E + CHUNK_E - 1) / CHUNK_E) // 586

__device__ __forceinline__ unsigned short benc(float f) {
    union { float f; unsigned u; } t; t.f = f;
    unsigned r = t.u + 0x7FFFu + ((t.u >> 16) & 1u);   // RNE
    return (unsigned short)(r >> 16);
}
__device__ __forceinline__ float blo(unsigned g) { return __uint_as_float(g << 16); }
__device__ __forceinline__ float bhi(unsigned g) { return __uint_as_float(g & 0xFFFF0000u); }

// ---- Pass 1: per-chunk histogram -> count matrix (deterministic, no atomics) ----
__global__ void __launch_bounds__(512)
partA1_kernel(const int* __restrict__ rows, int* __restrict__ cntmat) {
    __shared__ int l[NBUCK];
    int c0 = blockIdx.x * CHUNK_E;
    int c1 = c0 + CHUNK_E; if (c1 > NNZ_E) c1 = NNZ_E;
    for (int k = threadIdx.x; k < NBUCK; k += 512) l[k] = 0;
    __syncthreads();
    for (int e = c0 + threadIdx.x; e < c1; e += 512)
        atomicAdd(&l[rows[e] >> RSH], 1);
    __syncthreads();
    int* dst = cntmat + (size_t)blockIdx.x * NBUCK;
    for (int k = threadIdx.x; k < NBUCK; k += 512) dst[k] = l[k];
}

// ---- Column scan: runoff[p][b] = sum_{p'<p} cntmat[p'][b]; colTotal[b] ----
__global__ void colscanA_kernel(const int* __restrict__ cntmat, int* __restrict__ runoff,
                                int* __restrict__ colTotal) {
    int b = blockIdx.x * 64 + threadIdx.x;
    if (b >= NBUCK) return;
    int run = 0;
#pragma unroll 4
    for (int p = 0; p < NPART; ++p) {
        int v = cntmat[(size_t)p * NBUCK + b];
        runoff[(size_t)p * NBUCK + b] = run;
        run += v;
    }
    colTotal[b] = run;
}

// ---- Exclusive scan of colTotal -> bptr[NBUCK+1] ----
__global__ void colscanB_kernel(const int* __restrict__ colTotal, int* __restrict__ bptr) {
    __shared__ int t[512];
    int tid = threadIdx.x;
    int v = (tid < NBUCK) ? colTotal[tid] : 0;
    t[tid] = v;
    __syncthreads();
    for (int ofs = 1; ofs < 512; ofs <<= 1) {
        int a = (tid >= ofs) ? t[tid - ofs] : 0;
        __syncthreads();
        t[tid] += a;
        __syncthreads();
    }
    if (tid < NBUCK) bptr[tid] = t[tid] - v;
    if (tid == 511) bptr[NBUCK] = t[511];
}

// ---- Pass 2: scatter into bucket runs (cursor precomputed; nt stores) ----
__global__ void __launch_bounds__(512)
partA2_kernel(const int* __restrict__ rows, const int* __restrict__ cols,
              const float* __restrict__ vals, const int* __restrict__ runoff,
              const int* __restrict__ bptr, long long* __restrict__ tmp) {
    __shared__ int cur[NBUCK];
    int c0 = blockIdx.x * CHUNK_E;
    int c1 = c0 + CHUNK_E; if (c1 > NNZ_E) c1 = NNZ_E;
    const int* ro = runoff + (size_t)blockIdx.x * NBUCK;
    for (int k = threadIdx.x; k < NBUCK; k += 512) cur[k] = bptr[k] + ro[k];
    __syncthreads();
    for (int e = c0 + threadIdx.x; e < c1; e += 512) {
        int r = rows[e];
        int b = r >> RSH, rl = r & (RPB - 1);
        int p = atomicAdd(&cur[b], 1);
        unsigned lo = (unsigned)cols[e] | ((unsigned)rl << 18);
        unsigned hi = (unsigned)__float_as_int(vals[e]);
        long long packed = (long long)(((unsigned long long)hi << 32) | lo);
        __builtin_nontemporal_store(packed, &tmp[p]);
    }
}

// ---- Phase B: per-bucket counting sort -> packed 4B edges + rowptr ----
__global__ void __launch_bounds__(1024)
partB_kernel(const int* __restrict__ bptr, const long long* __restrict__ tmp,
             unsigned* __restrict__ fin, int* __restrict__ rowptr) {
    __shared__ int cnt[RPB];
    __shared__ int cur[RPB];
    int b = blockIdx.x;
    int bb0 = bptr[b], bb1 = bptr[b + 1];
    int tid = threadIdx.x;
    if (tid < RPB) cnt[tid] = 0;
    __syncthreads();
    for (int e = bb0 + tid; e < bb1; e += 1024) {
        unsigned lo = (unsigned)__builtin_nontemporal_load(&tmp[e]);
        atomicAdd(&cnt[lo >> 18], 1);
    }
    __syncthreads();
    int v = 0;
    if (tid < RPB) { v = cnt[tid]; cur[tid] = v; }
    __syncthreads();
    for (int ofs = 1; ofs < RPB; ofs <<= 1) {
        int a = (tid < RPB && tid >= ofs) ? cur[tid - ofs] : 0;
        __syncthreads();
        if (tid < RPB) cur[tid] += a;
        __syncthreads();
    }
    if (tid < RPB) {
        int excl = cur[tid] - v;
        int row = b * RPB + tid;
        if (row < NTOT) rowptr[row] = bb0 + excl;
        cur[tid] = excl;
    }
    if (b == NBUCK - 1 && tid == 0) rowptr[NTOT] = bb1;
    __syncthreads();
    for (int e = bb0 + tid; e < bb1; e += 1024) {
        long long t = __builtin_nontemporal_load(&tmp[e]);
        unsigned lo = (unsigned)t;
        unsigned hi = (unsigned)((unsigned long long)t >> 32);
        int rl = lo >> 18;
        int p = bb0 + atomicAdd(&cur[rl], 1);
        float val = __uint_as_float(hi);
        unsigned q = (unsigned)__float2int_rn(val * 16384.f);
        if (q > 16383u) q = 16383u;
        __builtin_nontemporal_store(((lo & 0x3FFFFu) << 14) | q, &fin[p]);
    }
}

// ---- x0h bf16-packed: uint j of row r = comps (2j, 2j+1) ----
__global__ void convert_kernel(const float2* __restrict__ user, const float2* __restrict__ item,
                               unsigned* __restrict__ xh2) {
    int i = blockIdx.x * blockDim.x + threadIdx.x;   // = row*32 + j
    if (i >= NTOT * 32) return;
    float2 v = (i < NUSERS * 32) ? user[i] : item[i - NUSERS * 32];
    xh2[i] = (unsigned)benc(v.x) | ((unsigned)benc(v.y) << 16);
}

// ---- SpMM: 8 rows/wave (8-lane octets), uint4 gathers, unroll 8, nt edge stream ----
__global__ void __launch_bounds__(256)
spmm_kernel(const int* __restrict__ rowptr, const unsigned* __restrict__ ed,
            const uint4* __restrict__ xin, uint4* __restrict__ yout,
            const float4* __restrict__ user, const float4* __restrict__ item,
            const uint4* __restrict__ y1, float4* __restrict__ out, int last) {
    int wid = blockIdx.x * (blockDim.x >> 6) + (threadIdx.x >> 6);
    int lane = threadIdx.x & 63;
    int oct = lane >> 3, s = lane & 7;
    int r = wid * 8 + oct;
    if (r >= NTOT) return;
    int start = rowptr[r];
    int end   = rowptr[r + 1];
    const float SCL = 1.f / 16384.f;
    float a0 = 0.f, a1 = 0.f, a2 = 0.f, a3 = 0.f, a4 = 0.f, a5 = 0.f, a6 = 0.f, a7 = 0.f;
    int i = start;
    for (; i + 8 <= end; i += 8) {
        unsigned e[8];
#pragma unroll
        for (int u = 0; u < 8; ++u) e[u] = __builtin_nontemporal_load(&ed[i + u]);
        uint4 g[8];
#pragma unroll
        for (int u = 0; u < 8; ++u) g[u] = xin[(size_t)(e[u] >> 14) * 8 + s];
#pragma unroll
        for (int u = 0; u < 8; ++u) {
            float v = (float)(e[u] & 0x3FFFu) * SCL;
            a0 += v * blo(g[u].x); a1 += v * bhi(g[u].x);
            a2 += v * blo(g[u].y); a3 += v * bhi(g[u].y);
            a4 += v * blo(g[u].z); a5 += v * bhi(g[u].z);
            a6 += v * blo(g[u].w); a7 += v * bhi(g[u].w);
        }
    }
    for (; i < end; ++i) {
        unsigned e = __builtin_nontemporal_load(&ed[i]);
        uint4 g = xin[(size_t)(e >> 14) * 8 + s];
        float v = (float)(e & 0x3FFFu) * SCL;
        a0 += v * blo(g.x); a1 += v * bhi(g.x);
        a2 += v * blo(g.y); a3 += v * bhi(g.y);
        a4 += v * blo(g.z); a5 += v * bhi(g.z);
        a6 += v * blo(g.w); a7 += v * bhi(g.w);
    }
    if (!last) {
        uint4 o;
        o.x = (unsigned)benc(a0) | ((unsigned)benc(a1) << 16);
        o.y = (unsigned)benc(a2) | ((unsigned)benc(a3) << 16);
        o.z = (unsigned)benc(a4) | ((unsigned)benc(a5) << 16);
        o.w = (unsigned)benc(a6) | ((unsigned)benc(a7) << 16);
        yout[(size_t)r * 8 + s] = o;
    } else {
        size_t f4 = (size_t)r * 16 + 2 * s;   // float4 index of comps [8s, 8s+4)
        float4 x0a = (r < NUSERS) ? user[f4]     : item[f4     - (size_t)NUSERS * 16];
        float4 x0b = (r < NUSERS) ? user[f4 + 1] : item[f4 + 1 - (size_t)NUSERS * 16];
        uint4 u1 = y1[(size_t)r * 8 + s];
        uint4 u2 = xin[(size_t)r * 8 + s];   // layer-3 input IS y2
        float4 oa, ob;
        oa.x = 0.25f * (x0a.x + blo(u1.x) + blo(u2.x) + a0);
        oa.y = 0.25f * (x0a.y + bhi(u1.x) + bhi(u2.x) + a1);
        oa.z = 0.25f * (x0a.z + blo(u1.y) + blo(u2.y) + a2);
        oa.w = 0.25f * (x0a.w + bhi(u1.y) + bhi(u2.y) + a3);
        ob.x = 0.25f * (x0b.x + blo(u1.z) + blo(u2.z) + a4);
        ob.y = 0.25f * (x0b.y + bhi(u1.z) + bhi(u2.z) + a5);
        ob.z = 0.25f * (x0b.z + blo(u1.w) + blo(u2.w) + a6);
        ob.w = 0.25f * (x0b.w + bhi(u1.w) + bhi(u2.w) + a7);
        out[f4]     = oa;
        out[f4 + 1] = ob;
    }
}

extern "C" void kernel_launch(void* const* d_in, const int* in_sizes, int n_in,
                              void* d_out, int out_size, void* d_ws, size_t ws_size,
                              hipStream_t stream) {
    const float* user = (const float*)d_in[0];
    const float* item = (const float*)d_in[1];
    const float* vals = (const float*)d_in[2];
    const int*   rows = (const int*)d_in[3];
    const int*   cols = (const int*)d_in[4];
    float* out = (float*)d_out;

    // ws layout (~98 MB): tmp 38.4M | fin 19.2M | bufA 19.2M | bufB 19.2M |
    // rowptr 600K | cntmat 687K | runoff 687K | colTotal 1.2K | bptr 1.2K
    char* w = (char*)d_ws;
    long long* tmp    = (long long*)w; w += (size_t)NNZ_E * 8;
    unsigned*  fin    = (unsigned*)w;  w += (size_t)NNZ_E * 4;
    unsigned*  bufA   = (unsigned*)w;  w += (size_t)NTOT * DIM * 2;   // x0h, later y2h
    unsigned*  bufB   = (unsigned*)w;  w += (size_t)NTOT * DIM * 2;   // y1h
    int*       rowptr = (int*)w;       w += (size_t)(NTOT + 1) * 4;
    int*       cntmat = (int*)w;       w += (size_t)NPART * NBUCK * 4;
    int*       runoff = (int*)w;       w += (size_t)NPART * NBUCK * 4;
    int*       colTotal = (int*)w;     w += (size_t)NBUCK * 4;
    int*       bptr   = (int*)w;

    const int blk = 256;
    const int gConv = (NTOT * 32 + blk - 1) / blk;       // 18750
    const int gSpmm = (NTOT / 8 + 3) / 4;                // 4688 (4 waves/block, 8 rows/wave)
    const int gCsA  = (NBUCK + 63) / 64;                 // 5

    // Deterministic two-pass counting partition
    partA1_kernel<<<NPART, 512, 0, stream>>>(rows, cntmat);
    colscanA_kernel<<<gCsA, 64, 0, stream>>>(cntmat, runoff, colTotal);
    colscanB_kernel<<<1, 512, 0, stream>>>(colTotal, bptr);
    partA2_kernel<<<NPART, 512, 0, stream>>>(rows, cols, vals, runoff, bptr, tmp);
    partB_kernel<<<NBUCK, 1024, 0, stream>>>(bptr, tmp, fin, rowptr);

    // Layer input in bf16
    convert_kernel<<<gConv, blk, 0, stream>>>((const float2*)user, (const float2*)item, bufA);

    // 3 propagation layers; layer 3 fuses the stage-mean into out
    spmm_kernel<<<gSpmm, blk, 0, stream>>>(rowptr, fin, (const uint4*)bufA, (uint4*)bufB,
                                           (const float4*)user, (const float4*)item,
                                           (const uint4*)bufB, (float4*)out, 0);  // y1=bufB
    spmm_kernel<<<gSpmm, blk, 0, stream>>>(rowptr, fin, (const uint4*)bufB, (uint4*)bufA,
                                           (const float4*)user, (const float4*)item,
                                           (const uint4*)bufB, (float4*)out, 0);  // y2=bufA
    spmm_kernel<<<gSpmm, blk, 0, stream>>>(rowptr, fin, (const uint4*)bufA, (uint4*)bufA,
                                           (const float4*)user, (const float4*)item,
                                           (const uint4*)bufB, (float4*)out, 1);  // fused mean
}

// Round 8
// 531.294 us; speedup vs baseline: 1.6313x; 1.6313x over previous
//
#include <hip/hip_runtime.h>

// LightGCN on MI355X (gfx950). Round 8.
// R7 lesson (hard evidence): nontemporal STORES on scattered writes bypass L2
// write-coalescing -> line-granularity write amplification (partB fin: 19MB logical
// -> 200MB written, 185us). ALL nontemporal ops removed; L2 write-back is what makes
// windowed scatters cheap. Keeping R7's validated deterministic count-matrix
// partition (partA1+colscans stayed off the top-5), now with transposed cntmatT so
// run-offset scans are per-bucket coalesced block scans (293 blocks).
// spmm = R6's exact version (best measured ~95-104us/layer).

#define NUSERS 100000
#define NITEMS 50000
#define NTOT   150000
#define DIM    64
#define NNZ_E  4800000

#define RPB     512                               // rows per bucket
#define RSH     9
#define NBUCK   ((NTOT + RPB - 1) / RPB)          // 293
#define CHUNK_E 8192
#define NPART   ((NNZ_E + CHUNK_E - 1) / CHUNK_E) // 586

__device__ __forceinline__ unsigned short benc(float f) {
    union { float f; unsigned u; } t; t.f = f;
    unsigned r = t.u + 0x7FFFu + ((t.u >> 16) & 1u);   // RNE
    return (unsigned short)(r >> 16);
}
__device__ __forceinline__ float blo(unsigned g) { return __uint_as_float(g << 16); }
__device__ __forceinline__ float bhi(unsigned g) { return __uint_as_float(g & 0xFFFF0000u); }

// ---- Pass 1: per-chunk LDS histogram -> TRANSPOSED count matrix cntmatT[b][p] ----
__global__ void __launch_bounds__(512)
partA1_kernel(const int* __restrict__ rows, int* __restrict__ cntmatT) {
    __shared__ int l[NBUCK];
    int p = blockIdx.x;
    int c0 = p * CHUNK_E;
    int c1 = c0 + CHUNK_E; if (c1 > NNZ_E) c1 = NNZ_E;
    for (int k = threadIdx.x; k < NBUCK; k += 512) l[k] = 0;
    __syncthreads();
    for (int e = c0 + threadIdx.x; e < c1; e += 512)
        atomicAdd(&l[rows[e] >> RSH], 1);
    __syncthreads();
    for (int k = threadIdx.x; k < NBUCK; k += 512)
        cntmatT[(size_t)k * NPART + p] = l[k];
}

// ---- Per-bucket run-offset scan: block b scans cntmatT[b][0..NPART) ----
// runoffT[b][p] = exclusive prefix; colTotal[b] = bucket total.
__global__ void __launch_bounds__(1024)
colscan1_kernel(const int* __restrict__ cntmatT, int* __restrict__ runoffT,
                int* __restrict__ colTotal) {
    __shared__ int t[1024];
    int b = blockIdx.x;
    int tid = threadIdx.x;
    int v = (tid < NPART) ? cntmatT[(size_t)b * NPART + tid] : 0;
    t[tid] = v;
    __syncthreads();
    for (int ofs = 1; ofs < 1024; ofs <<= 1) {
        int a = (tid >= ofs) ? t[tid - ofs] : 0;
        __syncthreads();
        t[tid] += a;
        __syncthreads();
    }
    if (tid < NPART) runoffT[(size_t)b * NPART + tid] = t[tid] - v;
    if (tid == NPART - 1) colTotal[b] = t[tid];
}

// ---- Exclusive scan of colTotal -> bptr[NBUCK+1] ----
__global__ void colscan2_kernel(const int* __restrict__ colTotal, int* __restrict__ bptr) {
    __shared__ int t[512];
    int tid = threadIdx.x;
    int v = (tid < NBUCK) ? colTotal[tid] : 0;
    t[tid] = v;
    __syncthreads();
    for (int ofs = 1; ofs < 512; ofs <<= 1) {
        int a = (tid >= ofs) ? t[tid - ofs] : 0;
        __syncthreads();
        t[tid] += a;
        __syncthreads();
    }
    if (tid < NBUCK) bptr[tid] = t[tid] - v;
    if (tid == 511) bptr[NBUCK] = t[511];
}

// ---- Pass 2: scatter into bucket runs (cursors precomputed; regular stores) ----
// tmp word: x = col | (row_local << 18), y = val fp32 bits.
__global__ void __launch_bounds__(512)
partA2_kernel(const int* __restrict__ rows, const int* __restrict__ cols,
              const float* __restrict__ vals, const int* __restrict__ runoffT,
              const int* __restrict__ bptr, int2* __restrict__ tmp) {
    __shared__ int cur[NBUCK];
    int p = blockIdx.x;
    int c0 = p * CHUNK_E;
    int c1 = c0 + CHUNK_E; if (c1 > NNZ_E) c1 = NNZ_E;
    for (int k = threadIdx.x; k < NBUCK; k += 512)
        cur[k] = bptr[k] + runoffT[(size_t)k * NPART + p];
    __syncthreads();
    for (int e = c0 + threadIdx.x; e < c1; e += 512) {
        int r = rows[e];
        int b = r >> RSH, rl = r & (RPB - 1);
        int q = atomicAdd(&cur[b], 1);
        tmp[q] = make_int2(cols[e] | (rl << 18), __float_as_int(vals[e]));
    }
}

// ---- Phase B: per-bucket counting sort -> packed 4B edges + rowptr ----
__global__ void __launch_bounds__(1024)
partB_kernel(const int* __restrict__ bptr, const int2* __restrict__ tmp,
             unsigned* __restrict__ fin, int* __restrict__ rowptr) {
    __shared__ int cnt[RPB];
    __shared__ int cur[RPB];
    int b = blockIdx.x;
    int bb0 = bptr[b], bb1 = bptr[b + 1];
    int tid = threadIdx.x;
    if (tid < RPB) cnt[tid] = 0;
    __syncthreads();
    for (int e = bb0 + tid; e < bb1; e += 1024)
        atomicAdd(&cnt[((unsigned)tmp[e].x) >> 18], 1);
    __syncthreads();
    int v = 0;
    if (tid < RPB) { v = cnt[tid]; cur[tid] = v; }
    __syncthreads();
    for (int ofs = 1; ofs < RPB; ofs <<= 1) {
        int a = (tid < RPB && tid >= ofs) ? cur[tid - ofs] : 0;
        __syncthreads();
        if (tid < RPB) cur[tid] += a;
        __syncthreads();
    }
    if (tid < RPB) {
        int excl = cur[tid] - v;
        int row = b * RPB + tid;
        if (row < NTOT) rowptr[row] = bb0 + excl;
        cur[tid] = excl;
    }
    if (b == NBUCK - 1 && tid == 0) rowptr[NTOT] = bb1;
    __syncthreads();
    for (int e = bb0 + tid; e < bb1; e += 1024) {
        int2 t = tmp[e];
        int rl = ((unsigned)t.x) >> 18;
        int q = bb0 + atomicAdd(&cur[rl], 1);
        float val = __int_as_float(t.y);
        unsigned qq = (unsigned)__float2int_rn(val * 16384.f);
        if (qq > 16383u) qq = 16383u;
        fin[q] = (((unsigned)t.x & 0x3FFFFu) << 14) | qq;
    }
}

// ---- x0h bf16-packed: uint j of row r = comps (2j, 2j+1) ----
__global__ void convert_kernel(const float2* __restrict__ user, const float2* __restrict__ item,
                               unsigned* __restrict__ xh2) {
    int i = blockIdx.x * blockDim.x + threadIdx.x;   // = row*32 + j
    if (i >= NTOT * 32) return;
    float2 v = (i < NUSERS * 32) ? user[i] : item[i - NUSERS * 32];
    xh2[i] = (unsigned)benc(v.x) | ((unsigned)benc(v.y) << 16);
}

// ---- SpMM (R6 exact): 8 rows/wave, uint4 gathers, unroll 8, reg accumulation ----
__global__ void __launch_bounds__(256)
spmm_kernel(const int* __restrict__ rowptr, const unsigned* __restrict__ ed,
            const uint4* __restrict__ xin, uint4* __restrict__ yout,
            const float4* __restrict__ user, const float4* __restrict__ item,
            const uint4* __restrict__ y1, float4* __restrict__ out, int last) {
    int wid = blockIdx.x * (blockDim.x >> 6) + (threadIdx.x >> 6);
    int lane = threadIdx.x & 63;
    int oct = lane >> 3, s = lane & 7;
    int r = wid * 8 + oct;
    if (r >= NTOT) return;
    int start = rowptr[r];
    int end   = rowptr[r + 1];
    const float SCL = 1.f / 16384.f;
    float a0 = 0.f, a1 = 0.f, a2 = 0.f, a3 = 0.f, a4 = 0.f, a5 = 0.f, a6 = 0.f, a7 = 0.f;
    int i = start;
    for (; i + 8 <= end; i += 8) {
        unsigned e[8];
#pragma unroll
        for (int u = 0; u < 8; ++u) e[u] = ed[i + u];
        uint4 g[8];
#pragma unroll
        for (int u = 0; u < 8; ++u) g[u] = xin[(size_t)(e[u] >> 14) * 8 + s];
#pragma unroll
        for (int u = 0; u < 8; ++u) {
            float v = (float)(e[u] & 0x3FFFu) * SCL;
            a0 += v * blo(g[u].x); a1 += v * bhi(g[u].x);
            a2 += v * blo(g[u].y); a3 += v * bhi(g[u].y);
            a4 += v * blo(g[u].z); a5 += v * bhi(g[u].z);
            a6 += v * blo(g[u].w); a7 += v * bhi(g[u].w);
        }
    }
    for (; i < end; ++i) {
        unsigned e = ed[i];
        uint4 g = xin[(size_t)(e >> 14) * 8 + s];
        float v = (float)(e & 0x3FFFu) * SCL;
        a0 += v * blo(g.x); a1 += v * bhi(g.x);
        a2 += v * blo(g.y); a3 += v * bhi(g.y);
        a4 += v * blo(g.z); a5 += v * bhi(g.z);
        a6 += v * blo(g.w); a7 += v * bhi(g.w);
    }
    if (!last) {
        uint4 o;
        o.x = (unsigned)benc(a0) | ((unsigned)benc(a1) << 16);
        o.y = (unsigned)benc(a2) | ((unsigned)benc(a3) << 16);
        o.z = (unsigned)benc(a4) | ((unsigned)benc(a5) << 16);
        o.w = (unsigned)benc(a6) | ((unsigned)benc(a7) << 16);
        yout[(size_t)r * 8 + s] = o;
    } else {
        size_t f4 = (size_t)r * 16 + 2 * s;   // float4 index of comps [8s, 8s+4)
        float4 x0a = (r < NUSERS) ? user[f4]     : item[f4     - (size_t)NUSERS * 16];
        float4 x0b = (r < NUSERS) ? user[f4 + 1] : item[f4 + 1 - (size_t)NUSERS * 16];
        uint4 u1 = y1[(size_t)r * 8 + s];
        uint4 u2 = xin[(size_t)r * 8 + s];   // layer-3 input IS y2
        float4 oa, ob;
        oa.x = 0.25f * (x0a.x + blo(u1.x) + blo(u2.x) + a0);
        oa.y = 0.25f * (x0a.y + bhi(u1.x) + bhi(u2.x) + a1);
        oa.z = 0.25f * (x0a.z + blo(u1.y) + blo(u2.y) + a2);
        oa.w = 0.25f * (x0a.w + bhi(u1.y) + bhi(u2.y) + a3);
        ob.x = 0.25f * (x0b.x + blo(u1.z) + blo(u2.z) + a4);
        ob.y = 0.25f * (x0b.y + bhi(u1.z) + bhi(u2.z) + a5);
        ob.z = 0.25f * (x0b.z + blo(u1.w) + blo(u2.w) + a6);
        ob.w = 0.25f * (x0b.w + bhi(u1.w) + bhi(u2.w) + a7);
        out[f4]     = oa;
        out[f4 + 1] = ob;
    }
}

extern "C" void kernel_launch(void* const* d_in, const int* in_sizes, int n_in,
                              void* d_out, int out_size, void* d_ws, size_t ws_size,
                              hipStream_t stream) {
    const float* user = (const float*)d_in[0];
    const float* item = (const float*)d_in[1];
    const float* vals = (const float*)d_in[2];
    const int*   rows = (const int*)d_in[3];
    const int*   cols = (const int*)d_in[4];
    float* out = (float*)d_out;

    // ws layout (~98 MB): tmp 38.4M | fin 19.2M | bufA 19.2M | bufB 19.2M |
    // rowptr 600K | cntmatT 687K | runoffT 687K | colTotal 1.2K | bptr 1.2K
    char* w = (char*)d_ws;
    int2*     tmp      = (int2*)w;     w += (size_t)NNZ_E * 8;
    unsigned* fin      = (unsigned*)w; w += (size_t)NNZ_E * 4;
    unsigned* bufA     = (unsigned*)w; w += (size_t)NTOT * DIM * 2;   // x0h, later y2h
    unsigned* bufB     = (unsigned*)w; w += (size_t)NTOT * DIM * 2;   // y1h
    int*      rowptr   = (int*)w;      w += (size_t)(NTOT + 1) * 4;
    int*      cntmatT  = (int*)w;      w += (size_t)NPART * NBUCK * 4;
    int*      runoffT  = (int*)w;      w += (size_t)NPART * NBUCK * 4;
    int*      colTotal = (int*)w;      w += (size_t)NBUCK * 4;
    int*      bptr     = (int*)w;

    const int blk = 256;
    const int gConv = (NTOT * 32 + blk - 1) / blk;       // 18750
    const int gSpmm = (NTOT / 8 + 3) / 4;                // 4688 (4 waves/block, 8 rows/wave)

    // Deterministic two-pass counting partition (no global atomics, regular stores)
    partA1_kernel<<<NPART, 512, 0, stream>>>(rows, cntmatT);
    colscan1_kernel<<<NBUCK, 1024, 0, stream>>>(cntmatT, runoffT, colTotal);
    colscan2_kernel<<<1, 512, 0, stream>>>(colTotal, bptr);
    partA2_kernel<<<NPART, 512, 0, stream>>>(rows, cols, vals, runoffT, bptr, tmp);
    partB_kernel<<<NBUCK, 1024, 0, stream>>>(bptr, tmp, fin, rowptr);

    // Layer input in bf16
    convert_kernel<<<gConv, blk, 0, stream>>>((const float2*)user, (const float2*)item, bufA);

    // 3 propagation layers; layer 3 fuses the stage-mean into out
    spmm_kernel<<<gSpmm, blk, 0, stream>>>(rowptr, fin, (const uint4*)bufA, (uint4*)bufB,
                                           (const float4*)user, (const float4*)item,
                                           (const uint4*)bufB, (float4*)out, 0);  // y1=bufB
    spmm_kernel<<<gSpmm, blk, 0, stream>>>(rowptr, fin, (const uint4*)bufB, (uint4*)bufA,
                                           (const float4*)user, (const float4*)item,
                                           (const uint4*)bufB, (float4*)out, 0);  // y2=bufA
    spmm_kernel<<<gSpmm, blk, 0, stream>>>(rowptr, fin, (const uint4*)bufA, (uint4*)bufA,
                                           (const float4*)user, (const float4*)item,
                                           (const uint4*)bufB, (float4*)out, 1);  // fused mean
}